// Round 1
// baseline (1265.091 us; speedup 1.0000x reference)
//
#include <hip/hip_runtime.h>

#define FEAT 128

// Zero-fill d_out (harness re-poisons it to 0xAA before every timed launch).
__global__ __launch_bounds__(256) void zero_out_kernel(float* __restrict__ out, int n) {
    int i = blockIdx.x * blockDim.x + threadIdx.x;
    if (i < n) out[i] = 0.0f;
}

// One 32-lane group per contiguous chunk of atoms.
// lane l loads float4 f[atom][4l..4l+3]  -> 512B coalesced per group.
// Running scalar accumulator while segment id unchanged (ids are sorted);
// shuffle-reduce + one atomicAdd per segment transition.
__global__ __launch_bounds__(256) void atomwise_readout_kernel(
    const float* __restrict__ f,
    const int*   __restrict__ seg,
    const float* __restrict__ w,
    float*       __restrict__ out,
    int n_atoms, int chunk) {

    const int tid   = blockIdx.x * blockDim.x + threadIdx.x;
    const int group = tid >> 5;       // 32 lanes per atom-group
    const int lane  = tid & 31;

    long start = (long)group * chunk;
    if (start >= n_atoms) return;
    long end = start + chunk;
    if (end > n_atoms) end = n_atoms;

    // w_e: 128 floats; lane l holds w[4l..4l+3]
    const float4 w4 = ((const float4*)w)[lane];

    float acc = 0.0f;
    int cur = seg[start];

    for (long a = start; a < end; ++a) {
        const int s = seg[a];                                   // uniform across group -> broadcast
        const float4 v = ((const float4*)(f + (size_t)a * FEAT))[lane];
        if (s != cur) {                                          // rare (~1-2 per chunk), group-uniform
            float r = acc;
            #pragma unroll
            for (int off = 16; off; off >>= 1) r += __shfl_xor(r, off);  // masks <32: stays in 32-group
            if (lane == 0) atomicAdd(&out[cur], r);
            acc = 0.0f;
            cur = s;
        }
        acc += v.x * w4.x + v.y * w4.y + v.z * w4.z + v.w * w4.w;
    }

    // flush tail segment
    float r = acc;
    #pragma unroll
    for (int off = 16; off; off >>= 1) r += __shfl_xor(r, off);
    if (lane == 0) atomicAdd(&out[cur], r);
}

extern "C" void kernel_launch(void* const* d_in, const int* in_sizes, int n_in,
                              void* d_out, int out_size, void* d_ws, size_t ws_size,
                              hipStream_t stream) {
    const float* f   = (const float*)d_in[0];   // [n_atoms, 128] fp32
    const int*   seg = (const int*)d_in[1];     // [n_atoms] sorted int32
    // d_in[2] is n_graphs (scalar on device) -- out_size gives it on host
    const float* w   = (const float*)d_in[3];   // [128, 1] fp32
    float* out = (float*)d_out;

    const int n_atoms = in_sizes[1];

    zero_out_kernel<<<(out_size + 255) / 256, 256, 0, stream>>>(out, out_size);

    // ~16K groups -> chunk ~123 atoms; 8 groups per 256-thread block.
    const int target_groups = 16384;
    int chunk = (n_atoms + target_groups - 1) / target_groups;
    if (chunk < 1) chunk = 1;
    const int n_groups = (n_atoms + chunk - 1) / chunk;
    const int n_blocks = (n_groups + 7) / 8;

    atomwise_readout_kernel<<<n_blocks, 256, 0, stream>>>(f, seg, w, out, n_atoms, chunk);
}